// Round 1
// baseline (254.666 us; speedup 1.0000x reference)
//
#include <hip/hip_runtime.h>

// CRF NLL on MI355X.
// B=512, S=1024, T=32, fp32. Output: scalar sum_b(partition_b - score_b).
//
// Partition: exp-domain forward/backward matvec chains, 32 lanes per batch
// (2 batches per 64-lane wave), one wave per (batch-pair, direction):
// 512 blocks x 64 threads. Normalize every 4 steps (growth/step <= e^13,
// 4 steps << e^88 fp32 range). Emissions staged through double-buffered LDS
// with coalesced float4 loads, prefetch distance 4 steps.
//
// ws layout (floats):
//   [0,       16384) fwd A   : b*32+j  (exp(alpha_511 - Lf), max-normalized)
//   [16384,   32768) bwd B   : b*32+j  (exp(beta_511  - Lb))
//   [32768,   33280) Lf[b]
//   [33280,   33792) Lb[b]

#define B_N 512
#define S_N 1024
#define T_N 32

__device__ __forceinline__ float half_max32(float v) {
    #pragma unroll
    for (int d = 16; d > 0; d >>= 1) v = fmaxf(v, __shfl_xor(v, d, 32));
    return v;
}
__device__ __forceinline__ float half_sum32(float v) {
    #pragma unroll
    for (int d = 16; d > 0; d >>= 1) v += __shfl_xor(v, d, 32);
    return v;
}

__global__ __launch_bounds__(64) void crf_chain(
    const float* __restrict__ em, const float* __restrict__ mask,
    const float* __restrict__ trans, const float* __restrict__ startT,
    const float* __restrict__ endT, float* __restrict__ ws)
{
    __shared__ float buf[2][256];          // [dbuf][half*128 + row*32 + j]
    const int lane = threadIdx.x;          // 0..63
    const int j    = lane & 31;            // tag index
    const int half = lane >> 5;            // which batch of the pair
    const int pair = blockIdx.x >> 1;
    const int dir  = blockIdx.x & 1;       // 0 = forward, 1 = backward
    const int b    = pair * 2 + half;

    const float* eb = em + (size_t)b * (S_N * T_N);
    const float* mb = mask + b * S_N;

    // exp(transitions): fwd lane j holds column j (sum over i of A_i*ET[i][j]);
    // bwd lane j holds row j (sum over k of ET[j][k]*P_k).
    float et[32];
    if (dir == 0) {
        #pragma unroll
        for (int i = 0; i < 32; ++i) et[i] = __expf(trans[i * 32 + j]);
    } else {
        #pragma unroll
        for (int i = 0; i < 32; ++i) et[i] = __expf(trans[j * 32 + i]);
    }

    // init state: fwd alpha_0 = start + e[b][0][:], bwd beta_1023 = end
    float A, Lacc;
    {
        float a0 = (dir == 0) ? (startT[j] + eb[j]) : endT[j];
        float m  = half_max32(a0);
        A    = __expf(a0 - m);
        Lacc = m;
    }

    // stage group 0 (fwd rows t=1..4 ; bwd rows t=1020..1023)
    {
        const int t0 = (dir == 0) ? 1 : 1020;
        float4 v = *(const float4*)(eb + t0 * 32 + j * 4);
        *(float4*)&buf[0][half * 128 + j * 4] = v;
    }

    // 128 groups of 4 steps.
    // fwd: t = 1+4g+k, k=0..3 (g=127,k=3 -> t=512 treated as masked no-op)
    //      -> alpha_511 after 511 real steps.
    // bwd: u = t0+3-k descending, t0 = 1020-4g; last group ends at u=512
    //      -> beta_511 after 512 steps.
    for (int g = 0; g < 128; ++g) {
        const int cur = g & 1;
        const int t0  = (dir == 0) ? (1 + 4 * g) : (1020 - 4 * g);

        float4 nv;
        const bool hasNext = (g + 1 < 128);
        if (hasNext) {
            const int t0n = (dir == 0) ? (t0 + 4) : (t0 - 4);
            nv = *(const float4*)(eb + t0n * 32 + j * 4);
        }

        float mk0 = mb[t0 + 0], mk1 = mb[t0 + 1], mk2 = mb[t0 + 2], mk3 = mb[t0 + 3];
        if (dir == 0 && g == 127) mk3 = 0.0f;   // t=512 -> masked no-op

        float ee0 = __expf(buf[cur][half * 128 +  0 + j]);
        float ee1 = __expf(buf[cur][half * 128 + 32 + j]);
        float ee2 = __expf(buf[cur][half * 128 + 64 + j]);
        float ee3 = __expf(buf[cur][half * 128 + 96 + j]);

        if (dir == 0) {
            #pragma unroll
            for (int k = 0; k < 4; ++k) {
                const float ee = (k == 0) ? ee0 : (k == 1) ? ee1 : (k == 2) ? ee2 : ee3;
                const float mk = (k == 0) ? mk0 : (k == 1) ? mk1 : (k == 2) ? mk2 : mk3;
                float a0_ = 0.f, a1_ = 0.f, a2_ = 0.f, a3_ = 0.f;
                #pragma unroll
                for (int i = 0; i < 32; i += 4) {
                    a0_ = fmaf(__shfl(A, i + 0, 32), et[i + 0], a0_);
                    a1_ = fmaf(__shfl(A, i + 1, 32), et[i + 1], a1_);
                    a2_ = fmaf(__shfl(A, i + 2, 32), et[i + 2], a2_);
                    a3_ = fmaf(__shfl(A, i + 3, 32), et[i + 3], a3_);
                }
                const float cand = ((a0_ + a1_) + (a2_ + a3_)) * ee;
                A = (mk != 0.0f) ? cand : A;
            }
        } else {
            #pragma unroll
            for (int k = 0; k < 4; ++k) {
                const float ee = (k == 0) ? ee3 : (k == 1) ? ee2 : (k == 2) ? ee1 : ee0;
                const float mk = (k == 0) ? mk3 : (k == 1) ? mk2 : (k == 2) ? mk1 : mk0;
                const float P = A * ee;
                float a0_ = 0.f, a1_ = 0.f, a2_ = 0.f, a3_ = 0.f;
                #pragma unroll
                for (int i = 0; i < 32; i += 4) {
                    a0_ = fmaf(__shfl(P, i + 0, 32), et[i + 0], a0_);
                    a1_ = fmaf(__shfl(P, i + 1, 32), et[i + 1], a1_);
                    a2_ = fmaf(__shfl(P, i + 2, 32), et[i + 2], a2_);
                    a3_ = fmaf(__shfl(P, i + 3, 32), et[i + 3], a3_);
                }
                const float cand = (a0_ + a1_) + (a2_ + a3_);
                A = (mk != 0.0f) ? cand : A;
            }
        }

        // renormalize (exact semantics: scale A, bank log(scale))
        const float m = half_max32(A);
        A    = A * (1.0f / m);
        Lacc += __logf(m);

        if (hasNext) *(float4*)&buf[cur ^ 1][half * 128 + j * 4] = nv;
    }

    if (dir == 0) {
        ws[b * 32 + j] = A;
        if (j == 0) ws[32768 + b] = Lacc;
    } else {
        ws[16384 + b * 32 + j] = A;
        if (j == 0) ws[33280 + b] = Lacc;
    }
}

// partition_b = Lf + Lb + log(sum_j Af_j * Bb_j); atomicAdd(+partition_b)
__global__ __launch_bounds__(256) void crf_combine(
    const float* __restrict__ ws, float* __restrict__ out)
{
    const int gid = blockIdx.x * 256 + threadIdx.x;
    const int b = gid >> 5, j = gid & 31;
    const float p = ws[b * 32 + j] * ws[16384 + b * 32 + j];
    const float s = half_sum32(p);
    if (j == 0) {
        const float part = ws[32768 + b] + ws[33280 + b] + __logf(s);
        atomicAdd(out, part);
    }
}

// path score: one 64-thread block per batch; atomicAdd(-score_b)
__global__ __launch_bounds__(64) void crf_score(
    const float* __restrict__ em, const int* __restrict__ tags,
    const float* __restrict__ mask, const float* __restrict__ trans,
    const float* __restrict__ startT, const float* __restrict__ endT,
    float* __restrict__ out)
{
    __shared__ float tr[1024];
    for (int i = threadIdx.x; i < 1024; i += 64) tr[i] = trans[i];
    __syncthreads();

    const int b = blockIdx.x;
    const int*   tb = tags + b * S_N;
    const float* mb = mask + b * S_N;
    const float* eb = em + (size_t)b * (S_N * T_N);

    float part = 0.f, msum = 0.f;
    for (int s = threadIdx.x; s < S_N; s += 64) {
        const int tc = tb[s];
        if (s == 0) {
            part += startT[tc] + eb[tc];
            msum += mb[0];
        } else {
            const int   tp = tb[s - 1];
            const float mv = mb[s];
            part += mv * (eb[s * 32 + tc] + tr[tp * 32 + tc]);
            msum += mv;
        }
    }
    #pragma unroll
    for (int d = 32; d > 0; d >>= 1) {
        part += __shfl_xor(part, d, 64);
        msum += __shfl_xor(msum, d, 64);
    }
    if (threadIdx.x == 0) {
        const int last = (int)(msum + 0.5f) - 1;
        const int lt   = tb[last];
        atomicAdd(out, -(part + endT[lt]));
    }
}

extern "C" void kernel_launch(void* const* d_in, const int* in_sizes, int n_in,
                              void* d_out, int out_size, void* d_ws, size_t ws_size,
                              hipStream_t stream) {
    const float* em     = (const float*)d_in[0];
    const int*   tags   = (const int*)  d_in[1];
    const float* mask   = (const float*)d_in[2];
    const float* trans  = (const float*)d_in[3];
    const float* startT = (const float*)d_in[4];
    const float* endT   = (const float*)d_in[5];
    float* out = (float*)d_out;
    float* ws  = (float*)d_ws;

    hipMemsetAsync(out, 0, sizeof(float), stream);

    // 512 blocks = 256 batch-pairs x {fwd,bwd}; 1 wave each, ~2 blocks/CU
    hipLaunchKernelGGL(crf_chain, dim3(512), dim3(64), 0, stream,
                       em, mask, trans, startT, endT, ws);
    hipLaunchKernelGGL(crf_score, dim3(512), dim3(64), 0, stream,
                       em, tags, mask, trans, startT, endT, out);
    hipLaunchKernelGGL(crf_combine, dim3(64), dim3(256), 0, stream,
                       ws, out);
}

// Round 2
// 210.110 us; speedup vs baseline: 1.2121x; 1.2121x over previous
//
#include <hip/hip_runtime.h>

// CRF NLL on MI355X — round 2: transfer-matrix chunking via MFMA.
//
// partition_b = log( a0 . (prod_t M_t) . exp(end) ),  M_t[i][j] = exp(tr[i][j]+e_t[j]).
// 32 chunks x 32 matrices per batch; one wave per (b,chunk) computes the 32x32
// bf16 matrix product with mfma_f32_32x32x16_bf16 (left-mult chain P <- M_t * P,
// P kept as the B operand: C/D -> B conversion is an xor-32 half-swap, no LDS).
// Fixed 2^-7 per-matrix scaling (exact: added back as n_applied*7*ln2).
//
// ws layout: [0, 32MiB) chunk-product B-fragments (bf16, 512 uints per (b,c));
//            [32MiB, +64KiB) n_applied per (b,c) as float.

typedef __attribute__((ext_vector_type(8)))  short    short8;
typedef __attribute__((ext_vector_type(16))) float    f32x16;
typedef __attribute__((ext_vector_type(4)))  unsigned uint4v;

#define S_N 1024
#define T_N 32
#define B_N 512
#define L_CH 32
#define C_CH 32
#define SCALE_MUL 0.0078125f           // 2^-7 folded into exp(e)
#define SCALE_LOG 4.852030263919617f   // 7*ln2 per applied matrix

// pack two f32 (bit-views) into one dword of two bf16 (truncate): low short = lo
__device__ __forceinline__ unsigned pk2(unsigned lo, unsigned hi) {
    return __builtin_amdgcn_perm(hi, lo, 0x07060302u);
}
__device__ __forceinline__ short8 mk8(const unsigned* a) {
    uint4v u = {a[0], a[1], a[2], a[3]};
    return __builtin_bit_cast(short8, u);
}
__device__ __forceinline__ float bflo(unsigned u) { return __uint_as_float(u << 16); }
__device__ __forceinline__ float bfhi(unsigned u) { return __uint_as_float(u & 0xFFFF0000u); }

__global__ __launch_bounds__(256) void crf_chunk(
    const float* __restrict__ em, const float* __restrict__ mask,
    const float* __restrict__ trans, unsigned* __restrict__ wsf,
    float* __restrict__ wsn)
{
    __shared__ float elds[4][L_CH * T_N];
    const int wib  = threadIdx.x >> 6;
    const int lane = threadIdx.x & 63;
    const int n    = lane & 31;
    const int h    = lane >> 5;
    const int wave = blockIdx.x * 4 + wib;
    const int b    = wave >> 5;
    const int c    = wave & (C_CH - 1);

    float* my = elds[wib];
    const float* eb = em + ((size_t)b * S_N + c * L_CH) * T_N;

    // stage ee = exp(e)*2^-7 for the chunk's 32 rows (coalesced float4)
    #pragma unroll
    for (int q = 0; q < 4; ++q) {
        const int flat = q * 256 + lane * 4;
        float4 v = *(const float4*)(eb + flat);
        v.x = __expf(v.x) * SCALE_MUL;
        v.y = __expf(v.y) * SCALE_MUL;
        v.z = __expf(v.z) * SCALE_MUL;
        v.w = __expf(v.w) * SCALE_MUL;
        *(float4*)(my + flat) = v;
    }
    __syncthreads();

    // exp(trans) rows for A fragments: A[m=n][k], k = 8h+j (A1), 16+8h+j (A2)
    float etA[16];
    #pragma unroll
    for (int j = 0; j < 8; ++j) {
        etA[j]     = __expf(trans[n * 32 + 8 * h + j]);
        etA[8 + j] = __expf(trans[n * 32 + 16 + 8 * h + j]);
    }

    // P = identity, held as B fragments (B[k][n]: lane n+32h holds k=8h+j / 16+8h+j)
    unsigned bB1[4] = {0u, 0u, 0u, 0u}, bB2[4] = {0u, 0u, 0u, 0u};
    {
        const int j1 = n - 8 * h;
        if (j1 >= 0 && j1 < 8) bB1[j1 >> 1] |= 0x3F80u << (16 * (j1 & 1));
        const int j2 = n - 16 - 8 * h;
        if (j2 >= 0 && j2 < 8) bB2[j2 >> 1] |= 0x3F80u << (16 * (j2 & 1));
    }

    const f32x16 Zacc = {};
    const int rmin = (c == 0) ? 1 : 0;   // t=0 has no transition matrix
    float napp = 0.0f;
    const float* mb = mask + (size_t)b * S_N + c * L_CH;

    for (int r = L_CH - 1; r >= rmin; --r) {
        const float mv = mb[r];
        if (mv == 0.0f) continue;        // masked step = identity
        napp += 1.0f;

        // ---- build A fragments: A[m][k] = exp(tr[m][k]) * ee_t[k] ----
        const float* er = my + r * 32;
        const float4 e0 = *(const float4*)(er + 8 * h);
        const float4 e1 = *(const float4*)(er + 8 * h + 4);
        const float4 e2 = *(const float4*)(er + 16 + 8 * h);
        const float4 e3 = *(const float4*)(er + 16 + 8 * h + 4);
        unsigned a1[4], a2[4];
        a1[0] = pk2(__float_as_uint(etA[0] * e0.x),  __float_as_uint(etA[1] * e0.y));
        a1[1] = pk2(__float_as_uint(etA[2] * e0.z),  __float_as_uint(etA[3] * e0.w));
        a1[2] = pk2(__float_as_uint(etA[4] * e1.x),  __float_as_uint(etA[5] * e1.y));
        a1[3] = pk2(__float_as_uint(etA[6] * e1.z),  __float_as_uint(etA[7] * e1.w));
        a2[0] = pk2(__float_as_uint(etA[8] * e2.x),  __float_as_uint(etA[9] * e2.y));
        a2[1] = pk2(__float_as_uint(etA[10] * e2.z), __float_as_uint(etA[11] * e2.w));
        a2[2] = pk2(__float_as_uint(etA[12] * e3.x), __float_as_uint(etA[13] * e3.y));
        a2[3] = pk2(__float_as_uint(etA[14] * e3.z), __float_as_uint(etA[15] * e3.w));

        // ---- P_new = M * P  (K=32 split into two MFMAs) ----
        f32x16 D = __builtin_amdgcn_mfma_f32_32x32x16_bf16(mk8(a1), mk8(bB1), Zacc, 0, 0, 0);
        D        = __builtin_amdgcn_mfma_f32_32x32x16_bf16(mk8(a2), mk8(bB2), D,    0, 0, 0);

        // ---- C/D layout -> next B fragments (round-to-nearest-ish, xor-32 swap) ----
        unsigned p[8], s[8];
        #pragma unroll
        for (int i = 0; i < 8; ++i) {
            const unsigned u0 = __float_as_uint(D[2 * i])     + 0x8000u;
            const unsigned u1 = __float_as_uint(D[2 * i + 1]) + 0x8000u;
            p[i] = pk2(u0, u1);
        }
        #pragma unroll
        for (int i = 0; i < 8; ++i) s[i] = __shfl_xor(p[i], 32);
        bB1[0] = h ? s[2] : p[0];
        bB1[1] = h ? s[3] : p[1];
        bB1[2] = h ? p[2] : s[0];
        bB1[3] = h ? p[3] : s[1];
        bB2[0] = h ? s[6] : p[4];
        bB2[1] = h ? s[7] : p[5];
        bB2[2] = h ? p[6] : s[4];
        bB2[3] = h ? p[7] : s[5];
    }

    unsigned* dst = wsf + ((size_t)(b * C_CH + c) * 64 + lane) * 8;
    ((uint4*)dst)[0] = make_uint4(bB1[0], bB1[1], bB1[2], bB1[3]);
    ((uint4*)dst)[1] = make_uint4(bB2[0], bB2[1], bB2[2], bB2[3]);
    if (lane == 0) wsn[b * C_CH + c] = napp;
}

// alpha-vector sweep over the 32 chunk matrices; one wave per batch.
__global__ __launch_bounds__(256) void crf_combine(
    const float* __restrict__ em, const float* __restrict__ startT,
    const float* __restrict__ endT, const unsigned* __restrict__ wsf,
    const float* __restrict__ wsn, float* __restrict__ out)
{
    const int lane = threadIdx.x & 63;
    const int n = lane & 31, h = lane >> 5;
    const int b = blockIdx.x * 4 + (threadIdx.x >> 6);

    float a0 = startT[n] + em[(size_t)b * S_N * T_N + n];
    float m = a0;
    #pragma unroll
    for (int d = 16; d > 0; d >>= 1) m = fmaxf(m, __shfl_xor(m, d, 32));
    float A = __expf(a0 - m);
    float Lacc = m;
    float ntot = 0.0f;

    const uint4* fb = (const uint4*)(wsf + (size_t)b * C_CH * 512);
    uint4 q0 = fb[lane * 2];
    uint4 q1 = fb[lane * 2 + 1];

    for (int c = 0; c < C_CH; ++c) {
        uint4 n0 = q0, n1 = q1;
        if (c + 1 < C_CH) {                      // prefetch next chunk's fragment
            n0 = fb[(c + 1) * 128 + lane * 2];
            n1 = fb[(c + 1) * 128 + lane * 2 + 1];
        }
        ntot += wsn[b * C_CH + c];

        // A_new[n] = sum_k A[k] * P[k][n]; this lane covers k=8h+j and 16+8h+j
        float part = 0.0f;
        part = fmaf(__shfl(A, 8 * h + 0, 32), bflo(q0.x), part);
        part = fmaf(__shfl(A, 8 * h + 1, 32), bfhi(q0.x), part);
        part = fmaf(__shfl(A, 8 * h + 2, 32), bflo(q0.y), part);
        part = fmaf(__shfl(A, 8 * h + 3, 32), bfhi(q0.y), part);
        part = fmaf(__shfl(A, 8 * h + 4, 32), bflo(q0.z), part);
        part = fmaf(__shfl(A, 8 * h + 5, 32), bfhi(q0.z), part);
        part = fmaf(__shfl(A, 8 * h + 6, 32), bflo(q0.w), part);
        part = fmaf(__shfl(A, 8 * h + 7, 32), bfhi(q0.w), part);
        part = fmaf(__shfl(A, 16 + 8 * h + 0, 32), bflo(q1.x), part);
        part = fmaf(__shfl(A, 16 + 8 * h + 1, 32), bfhi(q1.x), part);
        part = fmaf(__shfl(A, 16 + 8 * h + 2, 32), bflo(q1.y), part);
        part = fmaf(__shfl(A, 16 + 8 * h + 3, 32), bfhi(q1.y), part);
        part = fmaf(__shfl(A, 16 + 8 * h + 4, 32), bflo(q1.z), part);
        part = fmaf(__shfl(A, 16 + 8 * h + 5, 32), bfhi(q1.z), part);
        part = fmaf(__shfl(A, 16 + 8 * h + 6, 32), bflo(q1.w), part);
        part = fmaf(__shfl(A, 16 + 8 * h + 7, 32), bfhi(q1.w), part);
        part += __shfl_xor(part, 32);            // fold the two half-wave partials

        float mm = part;
        #pragma unroll
        for (int d = 16; d > 0; d >>= 1) mm = fmaxf(mm, __shfl_xor(mm, d, 32));
        A = part / mm;
        Lacc += __logf(mm);
        q0 = n0; q1 = n1;
    }

    float v = A * __expf(endT[n]);
    #pragma unroll
    for (int d = 16; d > 0; d >>= 1) v += __shfl_xor(v, d, 32);
    if (lane == 0) atomicAdd(out, Lacc + __logf(v) + ntot * SCALE_LOG);
}

// path score: one 64-thread block per batch; atomicAdd(-score_b)
__global__ __launch_bounds__(64) void crf_score(
    const float* __restrict__ em, const int* __restrict__ tags,
    const float* __restrict__ mask, const float* __restrict__ trans,
    const float* __restrict__ startT, const float* __restrict__ endT,
    float* __restrict__ out)
{
    __shared__ float tr[1024];
    for (int i = threadIdx.x; i < 1024; i += 64) tr[i] = trans[i];
    __syncthreads();

    const int b = blockIdx.x;
    const int*   tb = tags + (size_t)b * S_N;
    const float* mb = mask + (size_t)b * S_N;
    const float* eb = em + (size_t)b * (S_N * T_N);

    float part = 0.f, msum = 0.f;
    for (int s = threadIdx.x; s < S_N; s += 64) {
        const int tc = tb[s];
        if (s == 0) {
            part += startT[tc] + eb[tc];
            msum += mb[0];
        } else {
            const int   tp = tb[s - 1];
            const float mv = mb[s];
            part += mv * (eb[s * 32 + tc] + tr[tp * 32 + tc]);
            msum += mv;
        }
    }
    #pragma unroll
    for (int d = 32; d > 0; d >>= 1) {
        part += __shfl_xor(part, d, 64);
        msum += __shfl_xor(msum, d, 64);
    }
    if (threadIdx.x == 0) {
        const int last = (int)(msum + 0.5f) - 1;
        const int lt   = tb[last];
        atomicAdd(out, -(part + endT[lt]));
    }
}

extern "C" void kernel_launch(void* const* d_in, const int* in_sizes, int n_in,
                              void* d_out, int out_size, void* d_ws, size_t ws_size,
                              hipStream_t stream) {
    const float* em     = (const float*)d_in[0];
    const int*   tags   = (const int*)  d_in[1];
    const float* mask   = (const float*)d_in[2];
    const float* trans  = (const float*)d_in[3];
    const float* startT = (const float*)d_in[4];
    const float* endT   = (const float*)d_in[5];
    float* out = (float*)d_out;

    unsigned* wsf = (unsigned*)d_ws;                               // 32 MiB fragments
    float*    wsn = (float*)((char*)d_ws + (size_t)B_N * C_CH * 512 * 4);  // counts

    hipMemsetAsync(out, 0, sizeof(float), stream);

    // 512 batches x 32 chunks, 1 wave each -> 4096 blocks of 4 waves
    hipLaunchKernelGGL(crf_chunk, dim3(4096), dim3(256), 0, stream,
                       em, mask, trans, wsf, wsn);
    hipLaunchKernelGGL(crf_score, dim3(512), dim3(64), 0, stream,
                       em, tags, mask, trans, startT, endT, out);
    hipLaunchKernelGGL(crf_combine, dim3(128), dim3(256), 0, stream,
                       em, startT, endT, wsf, wsn, out);
}

// Round 3
// 192.428 us; speedup vs baseline: 1.3234x; 1.0919x over previous
//
#include <hip/hip_runtime.h>

// CRF NLL on MI355X — round 3: leaner MFMA transfer-matrix chain.
//
// partition_b = log( a0 . (prod_t M_t) . exp(end) ),  M_t[i][j] = exp(tr[i][j]+e_t[j]).
// 16 chunks x 64 matrices per batch; one wave per (b,chunk): left-mult chain
// P <- M_t*P (t descending) with P as the MFMA B operand. C/D -> B conversion
// via v_permlane32_swap_b32 (gfx950), packing via v_cvt_pk_bf16_f32, mask via
// one __ballot -> scalar bit tests. Path score fused into the chunk kernel.
// Fixed 2^-7 per-matrix scaling (exact: added back as napp*7*ln2).
//
// ws layout (bytes):
//   [0, 16MiB)            chunk-product B-fragments (512 dwords per (b,c))
//   [16MiB, +2KiB)        ws_msum[b]   (atomic-accumulated mask sums)
//   [16MiB+2K, +2KiB)     ws_score[b]  (atomic-accumulated path scores)
//   [16MiB+4K, +32KiB)    ws_napp[b*16+c]

typedef __attribute__((ext_vector_type(8)))  short    short8;
typedef __attribute__((ext_vector_type(16))) float    f32x16;
typedef __attribute__((ext_vector_type(4)))  unsigned uint4v;
typedef __attribute__((ext_vector_type(2)))  unsigned uint2v;

#define S_N 1024
#define T_N 32
#define B_N 512
#define L_CH 64
#define C_CH 16
#define SCALE_MUL 0.0078125f           // 2^-7 folded into exp(e)
#define SCALE_LOG 4.852030263919617f   // 7*ln2 per applied matrix

#define WS_FRAG_DW ((size_t)B_N * C_CH * 512)          // 4M dwords = 16 MiB
#define WS_MSUM_OFF (WS_FRAG_DW)                       // float index
#define WS_SCORE_OFF (WS_FRAG_DW + 512)
#define WS_NAPP_OFF (WS_FRAG_DW + 1024)

// ---- pack two f32 -> dword of two bf16 (low short = first arg) ----
#if __has_builtin(__builtin_amdgcn_cvt_pk_bf16_f32)
typedef __attribute__((ext_vector_type(2))) __bf16 bf16x2;
__device__ __forceinline__ unsigned cvtpk(float lo, float hi) {
    return __builtin_bit_cast(unsigned, __builtin_amdgcn_cvt_pk_bf16_f32(lo, hi));
}
#else
__device__ __forceinline__ unsigned cvtpk(float lo, float hi) {
    const unsigned a = __float_as_uint(lo) + 0x8000u;
    const unsigned b = __float_as_uint(hi) + 0x8000u;
    return __builtin_amdgcn_perm(b, a, 0x07060302u);  // [a.hi16, b.hi16]
}
#endif

// ---- half-wave swap: a' = [a.lo | b.lo->hi],  b' = [a.hi->lo | b.hi] ----
#if __has_builtin(__builtin_amdgcn_permlane32_swap)
__device__ __forceinline__ void swap32(unsigned& a, unsigned& b) {
    uint2v r = __builtin_amdgcn_permlane32_swap(a, b, false, false);
    a = r[0]; b = r[1];
}
#else
__device__ __forceinline__ void swap32(unsigned& a, unsigned& b) {
    const int h = (threadIdx.x & 63) >> 5;
    const unsigned sa = (unsigned)__shfl_xor((int)a, 32, 64);
    const unsigned sb = (unsigned)__shfl_xor((int)b, 32, 64);
    const unsigned na = h ? sb : a;
    const unsigned nb = h ? b : sa;
    a = na; b = nb;
}
#endif

__device__ __forceinline__ short8 mk8(const unsigned* a) {
    uint4v u = {a[0], a[1], a[2], a[3]};
    return __builtin_bit_cast(short8, u);
}
__device__ __forceinline__ float bflo(unsigned u) { return __uint_as_float(u << 16); }
__device__ __forceinline__ float bfhi(unsigned u) { return __uint_as_float(u & 0xFFFF0000u); }

__global__ __launch_bounds__(256) void crf_chunk(
    const float* __restrict__ em, const int* __restrict__ tags,
    const float* __restrict__ mask, const float* __restrict__ trans,
    const float* __restrict__ startT, unsigned* __restrict__ wsf,
    float* __restrict__ wsflt)
{
    __shared__ float elds[4][L_CH * T_N];   // 4 waves x 8 KiB = 32 KiB
    const int wib  = threadIdx.x >> 6;
    const int lane = threadIdx.x & 63;
    const int n    = lane & 31;
    const int h    = lane >> 5;
    const int wave = blockIdx.x * 4 + wib;
    const int b    = wave >> 4;
    const int c    = wave & (C_CH - 1);

    float* my = elds[wib];
    const float* eb = em + ((size_t)b * S_N + c * L_CH) * T_N;

    // ---- stage ee = exp(e)*2^-7 for 64 rows (coalesced float4) ----
    #pragma unroll
    for (int q = 0; q < 8; ++q) {
        const int flat = q * 256 + lane * 4;
        float4 v = *(const float4*)(eb + flat);
        v.x = __expf(v.x) * SCALE_MUL;
        v.y = __expf(v.y) * SCALE_MUL;
        v.z = __expf(v.z) * SCALE_MUL;
        v.w = __expf(v.w) * SCALE_MUL;
        *(float4*)(my + flat) = v;
    }

    // ---- mask bits for this chunk (one ballot; scalar tests in the loop) ----
    const int s0 = c * L_CH;
    const float mv_l = mask[b * S_N + s0 + lane];
    unsigned long long mbits = __ballot(mv_l != 0.0f);
    if (c == 0) mbits &= ~1ull;            // t=0 has no transition matrix

    // ---- fused path-score partial (lane l <-> position s0+l) ----
    {
        const int s  = s0 + lane;
        const int tc = tags[b * S_N + s];
        int tp = __shfl_up(tc, 1, 64);
        float val;
        if (lane == 0) {
            if (c == 0) {
                val = startT[tc] + eb[tc];
            } else {
                tp = tags[b * S_N + s - 1];
                val = mv_l * (em[((size_t)b * S_N + s) * T_N + tc] + trans[tp * 32 + tc]);
            }
        } else {
            val = mv_l * (em[((size_t)b * S_N + s) * T_N + tc] + trans[tp * 32 + tc]);
        }
        float ms = mv_l;
        #pragma unroll
        for (int d = 32; d > 0; d >>= 1) {
            val += __shfl_xor(val, d, 64);
            ms  += __shfl_xor(ms,  d, 64);
        }
        if (lane == 0) {
            atomicAdd(&wsflt[WS_SCORE_OFF + b], val);
            atomicAdd(&wsflt[WS_MSUM_OFF + b], ms);
            wsflt[WS_NAPP_OFF + b * C_CH + c] = (float)__popcll(mbits);
        }
    }

    __syncthreads();

    // ---- exp(trans) rows for A fragments: A[m=n][k], k=8h+j / 16+8h+j ----
    float etA[16];
    #pragma unroll
    for (int j = 0; j < 8; ++j) {
        etA[j]     = __expf(trans[n * 32 + 8 * h + j]);
        etA[8 + j] = __expf(trans[n * 32 + 16 + 8 * h + j]);
    }

    // ---- P = identity as B fragments (B[k][n], lane n+32h holds k=8h+j / 16+8h+j)
    unsigned bB1[4] = {0u, 0u, 0u, 0u}, bB2[4] = {0u, 0u, 0u, 0u};
    {
        const int j1 = n - 8 * h;
        if (j1 >= 0 && j1 < 8) bB1[j1 >> 1] |= 0x3F80u << (16 * (j1 & 1));
        const int j2 = n - 16 - 8 * h;
        if (j2 >= 0 && j2 < 8) bB2[j2 >> 1] |= 0x3F80u << (16 * (j2 & 1));
    }

    const f32x16 Zacc = {};

    #pragma unroll 8
    for (int r = L_CH - 1; r >= 0; --r) {
        if (!((mbits >> r) & 1ull)) continue;   // masked / skipped step

        // A[m][k] = exp(tr[m][k]) * ee_r[k]
        const float* er = my + r * 32;
        const float4 e0 = *(const float4*)(er + 8 * h);
        const float4 e1 = *(const float4*)(er + 8 * h + 4);
        const float4 e2 = *(const float4*)(er + 16 + 8 * h);
        const float4 e3 = *(const float4*)(er + 16 + 8 * h + 4);
        unsigned a1[4], a2[4];
        a1[0] = cvtpk(etA[0]  * e0.x, etA[1]  * e0.y);
        a1[1] = cvtpk(etA[2]  * e0.z, etA[3]  * e0.w);
        a1[2] = cvtpk(etA[4]  * e1.x, etA[5]  * e1.y);
        a1[3] = cvtpk(etA[6]  * e1.z, etA[7]  * e1.w);
        a2[0] = cvtpk(etA[8]  * e2.x, etA[9]  * e2.y);
        a2[1] = cvtpk(etA[10] * e2.z, etA[11] * e2.w);
        a2[2] = cvtpk(etA[12] * e3.x, etA[13] * e3.y);
        a2[3] = cvtpk(etA[14] * e3.z, etA[15] * e3.w);

        // P_new = M * P  (K=32 as two MFMAs)
        f32x16 D = __builtin_amdgcn_mfma_f32_32x32x16_bf16(mk8(a1), mk8(bB1), Zacc, 0, 0, 0);
        D        = __builtin_amdgcn_mfma_f32_32x32x16_bf16(mk8(a2), mk8(bB2), D,    0, 0, 0);

        // C/D -> next B fragments: pack + 4 half-wave swaps
        unsigned p0 = cvtpk(D[0],  D[1]);
        unsigned p1 = cvtpk(D[2],  D[3]);
        unsigned p2 = cvtpk(D[4],  D[5]);
        unsigned p3 = cvtpk(D[6],  D[7]);
        unsigned p4 = cvtpk(D[8],  D[9]);
        unsigned p5 = cvtpk(D[10], D[11]);
        unsigned p6 = cvtpk(D[12], D[13]);
        unsigned p7 = cvtpk(D[14], D[15]);
        swap32(p0, p2); swap32(p1, p3); swap32(p4, p6); swap32(p5, p7);
        bB1[0] = p0; bB1[1] = p1; bB1[2] = p2; bB1[3] = p3;
        bB2[0] = p4; bB2[1] = p5; bB2[2] = p6; bB2[3] = p7;
    }

    unsigned* dst = wsf + ((size_t)(b * C_CH + c) * 64 + lane) * 8;
    ((uint4*)dst)[0] = make_uint4(bB1[0], bB1[1], bB1[2], bB1[3]);
    ((uint4*)dst)[1] = make_uint4(bB2[0], bB2[1], bB2[2], bB2[3]);
}

// alpha-vector sweep over the 16 chunk matrices; one wave per batch.
// Adds (partition_b - score_end_b - score_rest_b) into out.
__global__ __launch_bounds__(256) void crf_combine(
    const float* __restrict__ em, const int* __restrict__ tags,
    const float* __restrict__ startT, const float* __restrict__ endT,
    const unsigned* __restrict__ wsf, const float* __restrict__ wsflt,
    float* __restrict__ out)
{
    const int lane = threadIdx.x & 63;
    const int n = lane & 31, h = lane >> 5;
    const int b = blockIdx.x * 4 + (threadIdx.x >> 6);

    float a0 = startT[n] + em[(size_t)b * S_N * T_N + n];
    float m = a0;
    #pragma unroll
    for (int d = 16; d > 0; d >>= 1) m = fmaxf(m, __shfl_xor(m, d, 32));
    float A = __expf(a0 - m);
    float Lacc = m;
    float ntot = 0.0f;

    const uint4* fb = (const uint4*)(wsf + (size_t)b * C_CH * 512);
    uint4 q0 = fb[lane * 2];
    uint4 q1 = fb[lane * 2 + 1];

    for (int c = 0; c < C_CH; ++c) {
        uint4 n0 = q0, n1 = q1;
        if (c + 1 < C_CH) {                      // prefetch next chunk's fragment
            n0 = fb[(c + 1) * 128 + lane * 2];
            n1 = fb[(c + 1) * 128 + lane * 2 + 1];
        }
        ntot += wsflt[WS_NAPP_OFF + b * C_CH + c];

        // A_new[n] = sum_k A[k] * P[k][n]; this lane covers k=8h+j and 16+8h+j
        float part = 0.0f;
        part = fmaf(__shfl(A, 8 * h + 0, 32), bflo(q0.x), part);
        part = fmaf(__shfl(A, 8 * h + 1, 32), bfhi(q0.x), part);
        part = fmaf(__shfl(A, 8 * h + 2, 32), bflo(q0.y), part);
        part = fmaf(__shfl(A, 8 * h + 3, 32), bfhi(q0.y), part);
        part = fmaf(__shfl(A, 8 * h + 4, 32), bflo(q0.z), part);
        part = fmaf(__shfl(A, 8 * h + 5, 32), bfhi(q0.z), part);
        part = fmaf(__shfl(A, 8 * h + 6, 32), bflo(q0.w), part);
        part = fmaf(__shfl(A, 8 * h + 7, 32), bfhi(q0.w), part);
        part = fmaf(__shfl(A, 16 + 8 * h + 0, 32), bflo(q1.x), part);
        part = fmaf(__shfl(A, 16 + 8 * h + 1, 32), bfhi(q1.x), part);
        part = fmaf(__shfl(A, 16 + 8 * h + 2, 32), bflo(q1.y), part);
        part = fmaf(__shfl(A, 16 + 8 * h + 3, 32), bfhi(q1.y), part);
        part = fmaf(__shfl(A, 16 + 8 * h + 4, 32), bflo(q1.z), part);
        part = fmaf(__shfl(A, 16 + 8 * h + 5, 32), bfhi(q1.z), part);
        part = fmaf(__shfl(A, 16 + 8 * h + 6, 32), bflo(q1.w), part);
        part = fmaf(__shfl(A, 16 + 8 * h + 7, 32), bfhi(q1.w), part);
        part += __shfl_xor(part, 32);            // fold the two half-wave partials

        float mm = part;
        #pragma unroll
        for (int d = 16; d > 0; d >>= 1) mm = fmaxf(mm, __shfl_xor(mm, d, 32));
        A = part / mm;
        Lacc += __logf(mm);
        q0 = n0; q1 = n1;
    }

    float v = A * __expf(endT[n]);
    #pragma unroll
    for (int d = 16; d > 0; d >>= 1) v += __shfl_xor(v, d, 32);
    if (lane == 0) {
        const int len = (int)(wsflt[WS_MSUM_OFF + b] + 0.5f);
        const int lt  = tags[b * S_N + len - 1];
        const float res = Lacc + __logf(v) + ntot * SCALE_LOG
                          - endT[lt] - wsflt[WS_SCORE_OFF + b];
        atomicAdd(out, res);
    }
}

extern "C" void kernel_launch(void* const* d_in, const int* in_sizes, int n_in,
                              void* d_out, int out_size, void* d_ws, size_t ws_size,
                              hipStream_t stream) {
    const float* em     = (const float*)d_in[0];
    const int*   tags   = (const int*)  d_in[1];
    const float* mask   = (const float*)d_in[2];
    const float* trans  = (const float*)d_in[3];
    const float* startT = (const float*)d_in[4];
    const float* endT   = (const float*)d_in[5];
    float* out = (float*)d_out;

    unsigned* wsf   = (unsigned*)d_ws;
    float*    wsflt = (float*)d_ws;

    hipMemsetAsync(out, 0, sizeof(float), stream);
    // zero the atomic accumulators (msum + score, 4 KiB)
    hipMemsetAsync((char*)d_ws + WS_MSUM_OFF * 4, 0, 4096, stream);

    // 512 batches x 16 chunks, 1 wave each -> 2048 blocks of 4 waves
    hipLaunchKernelGGL(crf_chunk, dim3(2048), dim3(256), 0, stream,
                       em, tags, mask, trans, startT, wsf, wsflt);
    hipLaunchKernelGGL(crf_combine, dim3(128), dim3(256), 0, stream,
                       em, tags, startT, endT, wsf, wsflt, out);
}

// Round 4
// 178.252 us; speedup vs baseline: 1.4287x; 1.0795x over previous
//
#include <hip/hip_runtime.h>

// CRF NLL on MI355X — round 4: permutation-aligned MFMA chain (no cross-lane).
//
// partition_b = log( a0 . (prod_t M_t) . exp(end) ),  M_t = ET . diag(ee_t),
// ET[i][j]=exp(tr[i][j]), ee_t[j]=exp(e_t[j])*2^-7.
// Key trick: state rows are stored under permutation PI (swap 4-7<->8-11,
// 20-23<->24-27). Then the 32x32x16 MFMA C/D register order IS the next-step
// B operand order (slot rows == reg rows), so C->B conversion = 8 cvtpk, no
// shuffles. A = bf16(ET with PI-permuted columns) is loop-invariant.
// Chunks 0..7: forward products G_c; chunks 8..15: transposed products G_c^T
// (A = ET^T permuted; scale after MFMA) so the combine can run a row-vector
// chain from both ends (2 waves/batch, meet in LDS).
// LDS holds ee as packed bf16 pairs in D-reg-pair order: 2 ds_read_b128/step.
//
// ws: [0,16MiB) fragments (8 dw/lane); then msum[512], score[512], napp[8192].

typedef __attribute__((ext_vector_type(8)))  short    short8;
typedef __attribute__((ext_vector_type(16))) float    f32x16;
typedef __attribute__((ext_vector_type(4)))  unsigned uint4v;

#define S_N 1024
#define T_N 32
#define B_N 512
#define L_CH 64
#define C_CH 16
#define SCALE_MUL 0.0078125f           // 2^-7 folded into ee
#define SCALE_LOG 4.852030263919617f   // 7*ln2 per applied matrix

#define WS_FRAG_DW ((size_t)B_N * C_CH * 512)          // 16 MiB
#define WS_MSUM_OFF (WS_FRAG_DW)
#define WS_SCORE_OFF (WS_FRAG_DW + 512)
#define WS_NAPP_OFF (WS_FRAG_DW + 1024)

#if __has_builtin(__builtin_amdgcn_cvt_pk_bf16_f32)
typedef __attribute__((ext_vector_type(2))) __bf16 bf16x2;
__device__ __forceinline__ unsigned cvtpk(float lo, float hi) {
    return __builtin_bit_cast(unsigned, __builtin_amdgcn_cvt_pk_bf16_f32(lo, hi));
}
#else
__device__ __forceinline__ unsigned cvtpk(float lo, float hi) {
    const unsigned a = __float_as_uint(lo) + 0x8000u;
    const unsigned b = __float_as_uint(hi) + 0x8000u;
    return __builtin_amdgcn_perm(b, a, 0x07060302u);
}
#endif

__device__ __forceinline__ short8 mk8(const unsigned* a) {
    uint4v u = {a[0], a[1], a[2], a[3]};
    return __builtin_bit_cast(short8, u);
}
__device__ __forceinline__ float bflo(unsigned u) { return __uint_as_float(u << 16); }
__device__ __forceinline__ float bfhi(unsigned u) { return __uint_as_float(u & 0xFFFF0000u); }
// PI: involution swapping 4-7<->8-11 and 20-23<->24-27
__device__ __forceinline__ int PIx(int x) { return (x & ~12) | ((x & 4) << 1) | ((x & 8) >> 1); }

__global__ __launch_bounds__(256) void crf_chunk(
    const float* __restrict__ em, const int* __restrict__ tags,
    const float* __restrict__ mask, const float* __restrict__ trans,
    const float* __restrict__ startT, unsigned* __restrict__ wsf,
    float* __restrict__ wsflt)
{
    __shared__ unsigned elds[4][L_CH * 16];   // 4 waves x 4 KiB packed bf16 scales
    const int wib  = threadIdx.x >> 6;
    const int lane = threadIdx.x & 63;
    const int n    = lane & 31;
    const int h    = lane >> 5;
    const int wave = blockIdx.x * 4 + wib;
    const int b    = wave >> 4;
    const int c    = wave & (C_CH - 1);

    unsigned* my = elds[wib];
    const float* eb = em + ((size_t)b * S_N + c * L_CH) * T_N;

    // ---- stage packed scales: dword (r, m=h*8+q) = bf16x2(ee[r][base], ee[r][base+1])
    // base(m) covers even rows in D-reg-pair order.
    #pragma unroll
    for (int i = 0; i < 16; ++i) {
        const int flat = i * 64 + lane;
        const int r = flat >> 4, m = flat & 15;
        const int base = ((m & 4) << 2) + ((m & 2) << 2) + ((m & 1) << 1) + ((m >> 3) << 2);
        const float2 v = *(const float2*)(eb + r * 32 + base);
        my[r * 16 + m] = cvtpk(__expf(v.x) * SCALE_MUL, __expf(v.y) * SCALE_MUL);
    }

    // ---- mask ballot ----
    const int s0 = c * L_CH;
    const float mv_l = mask[b * S_N + s0 + lane];
    unsigned long long mbits = __ballot(mv_l != 0.0f);
    if (c == 0) mbits &= ~1ull;

    // ---- fused path-score partial ----
    {
        const int s  = s0 + lane;
        const int tc = tags[b * S_N + s];
        int tp = __shfl_up(tc, 1, 64);
        float val;
        if (lane == 0) {
            if (c == 0) {
                val = startT[tc] + eb[tc];
            } else {
                tp = tags[b * S_N + s - 1];
                val = mv_l * (em[((size_t)b * S_N + s) * T_N + tc] + trans[tp * 32 + tc]);
            }
        } else {
            val = mv_l * (em[((size_t)b * S_N + s) * T_N + tc] + trans[tp * 32 + tc]);
        }
        float ms = mv_l;
        #pragma unroll
        for (int d = 32; d > 0; d >>= 1) {
            val += __shfl_xor(val, d, 64);
            ms  += __shfl_xor(ms,  d, 64);
        }
        if (lane == 0) {
            atomicAdd(&wsflt[WS_SCORE_OFF + b], val);
            atomicAdd(&wsflt[WS_MSUM_OFF + b], ms);
            wsflt[WS_NAPP_OFF + b * C_CH + c] = (float)__popcll(mbits);
        }
    }
    __syncthreads();

    const bool fwdDir = (c < 8);
    const f32x16 Zacc = {};

    // ---- loop-invariant A fragments (PI-permuted columns / rows) ----
    unsigned A1[4], A2[4];
    #pragma unroll
    for (int j = 0; j < 4; ++j) {
        const int k1 = PIx(8 * h + 2 * j);        // PI maps even pairs to even pairs
        const int k2 = PIx(16 + 8 * h + 2 * j);
        if (fwdDir) {
            A1[j] = cvtpk(__expf(trans[n * 32 + k1]), __expf(trans[n * 32 + k1 + 1]));
            A2[j] = cvtpk(__expf(trans[n * 32 + k2]), __expf(trans[n * 32 + k2 + 1]));
        } else {
            A1[j] = cvtpk(__expf(trans[k1 * 32 + n]), __expf(trans[(k1 + 1) * 32 + n]));
            A2[j] = cvtpk(__expf(trans[k2 * 32 + n]), __expf(trans[(k2 + 1) * 32 + n]));
        }
    }
    const short8 A1v = mk8(A1), A2v = mk8(A2);
    const bool clean = ((mbits | (c == 0 ? 1ull : 0ull)) == ~0ull);

    if (fwdDir) {
        // D = identity in C layout; chain r descending: S = pack(D*s_r); D = ET_pi * S
        f32x16 D;
        #pragma unroll
        for (int i = 0; i < 16; ++i) {
            const int row = (i & 3) + 8 * (i >> 2) + 4 * h;
            D[i] = (row == n) ? 1.0f : 0.0f;
        }
        #define STEP_FWD(r_) { \
            const uint4 su = *(const uint4*)(my + (r_) * 16 + h * 8); \
            const uint4 sv = *(const uint4*)(my + (r_) * 16 + h * 8 + 4); \
            unsigned S[8]; \
            S[0] = cvtpk(D[0]  * bflo(su.x), D[1]  * bfhi(su.x)); \
            S[1] = cvtpk(D[2]  * bflo(su.y), D[3]  * bfhi(su.y)); \
            S[2] = cvtpk(D[4]  * bflo(su.z), D[5]  * bfhi(su.z)); \
            S[3] = cvtpk(D[6]  * bflo(su.w), D[7]  * bfhi(su.w)); \
            S[4] = cvtpk(D[8]  * bflo(sv.x), D[9]  * bfhi(sv.x)); \
            S[5] = cvtpk(D[10] * bflo(sv.y), D[11] * bfhi(sv.y)); \
            S[6] = cvtpk(D[12] * bflo(sv.z), D[13] * bfhi(sv.z)); \
            S[7] = cvtpk(D[14] * bflo(sv.w), D[15] * bfhi(sv.w)); \
            f32x16 t_ = __builtin_amdgcn_mfma_f32_32x32x16_bf16(A1v, mk8(&S[0]), Zacc, 0, 0, 0); \
            D = __builtin_amdgcn_mfma_f32_32x32x16_bf16(A2v, mk8(&S[4]), t_, 0, 0, 0); \
        }
        if (clean) {
            #pragma unroll 4
            for (int r = 63; r >= 1; --r) STEP_FWD(r);
            if (c != 0) STEP_FWD(0);
        } else {
            for (int r = 63; r >= 0; --r)
                if ((mbits >> r) & 1ull) STEP_FWD(r);
        }
        unsigned* dst = wsf + ((size_t)(b * C_CH + c) * 64 + lane) * 8;
        ((uint4*)dst)[0] = make_uint4(cvtpk(D[0], D[1]),  cvtpk(D[2], D[3]),
                                      cvtpk(D[4], D[5]),  cvtpk(D[6], D[7]));
        ((uint4*)dst)[1] = make_uint4(cvtpk(D[8], D[9]),  cvtpk(D[10], D[11]),
                                      cvtpk(D[12], D[13]), cvtpk(D[14], D[15]));
    } else {
        // transposed chain, r ascending: D = ET^T_pi * S; S = pack(D*s_r)
        unsigned S[8] = {0u, 0u, 0u, 0u, 0u, 0u, 0u, 0u};
        {   // identity in permuted-B layout: slot with PI(k)==n gets 1.0
            const int pn = PIx(n);                 // PI is an involution
            if (((pn >> 3) & 1) == h) {
                const int j = pn & 7;
                const unsigned val = 0x3F80u << (16 * (j & 1));
                if (n < 16) S[j >> 1] |= val; else S[4 + (j >> 1)] |= val;
            }
        }
        #define STEP_BWD(r_) { \
            f32x16 t_ = __builtin_amdgcn_mfma_f32_32x32x16_bf16(A1v, mk8(&S[0]), Zacc, 0, 0, 0); \
            t_ = __builtin_amdgcn_mfma_f32_32x32x16_bf16(A2v, mk8(&S[4]), t_, 0, 0, 0); \
            const uint4 su = *(const uint4*)(my + (r_) * 16 + h * 8); \
            const uint4 sv = *(const uint4*)(my + (r_) * 16 + h * 8 + 4); \
            S[0] = cvtpk(t_[0]  * bflo(su.x), t_[1]  * bfhi(su.x)); \
            S[1] = cvtpk(t_[2]  * bflo(su.y), t_[3]  * bfhi(su.y)); \
            S[2] = cvtpk(t_[4]  * bflo(su.z), t_[5]  * bfhi(su.z)); \
            S[3] = cvtpk(t_[6]  * bflo(su.w), t_[7]  * bfhi(su.w)); \
            S[4] = cvtpk(t_[8]  * bflo(sv.x), t_[9]  * bfhi(sv.x)); \
            S[5] = cvtpk(t_[10] * bflo(sv.y), t_[11] * bfhi(sv.y)); \
            S[6] = cvtpk(t_[12] * bflo(sv.z), t_[13] * bfhi(sv.z)); \
            S[7] = cvtpk(t_[14] * bflo(sv.w), t_[15] * bfhi(sv.w)); \
        }
        if (clean) {
            #pragma unroll 4
            for (int r = 0; r < 64; ++r) STEP_BWD(r);
        } else {
            for (int r = 0; r < 64; ++r)
                if ((mbits >> r) & 1ull) STEP_BWD(r);
        }
        unsigned* dst = wsf + ((size_t)(b * C_CH + c) * 64 + lane) * 8;
        ((uint4*)dst)[0] = make_uint4(S[0], S[1], S[2], S[3]);
        ((uint4*)dst)[1] = make_uint4(S[4], S[5], S[6], S[7]);
    }
}

// two waves per batch: wave0 = alpha over chunks 0..7, wave1 = e^T over 15..8
__global__ __launch_bounds__(128) void crf_combine(
    const float* __restrict__ em, const int* __restrict__ tags,
    const float* __restrict__ startT, const float* __restrict__ endT,
    const unsigned* __restrict__ wsf, const float* __restrict__ wsflt,
    float* __restrict__ out)
{
    __shared__ float sm[68];
    const int lane = threadIdx.x & 63;
    const int w = threadIdx.x >> 6;
    const int n = lane & 31, h = lane >> 5;
    const int b = blockIdx.x;

    int idxA[8], idxB[8];
    #pragma unroll
    for (int j = 0; j < 8; ++j) {
        idxA[j] = PIx(8 * h + j);
        idxB[j] = PIx(16 + 8 * h + j);
    }

    float a0 = (w == 0) ? (startT[n] + em[(size_t)b * S_N * T_N + n]) : endT[n];
    float m = a0;
    #pragma unroll
    for (int d = 16; d > 0; d >>= 1) m = fmaxf(m, __shfl_xor(m, d, 32));
    float A = __expf(a0 - m);
    float Lacc = m;
    float ntot = 0.0f;

    const uint4* fb = (const uint4*)(wsf + (size_t)b * C_CH * 512);
    const int c0 = (w == 0) ? 0 : 15;
    const int dc = (w == 0) ? 1 : -1;
    uint4 q0 = fb[c0 * 128 + lane * 2];
    uint4 q1 = fb[c0 * 128 + lane * 2 + 1];

    for (int i = 0; i < 8; ++i) {
        const int c = c0 + i * dc;
        uint4 n0 = q0, n1 = q1;
        if (i + 1 < 8) {
            n0 = fb[(c + dc) * 128 + lane * 2];
            n1 = fb[(c + dc) * 128 + lane * 2 + 1];
        }
        ntot += wsflt[WS_NAPP_OFF + b * C_CH + c];

        float p0 = 0.f, p1 = 0.f, p2 = 0.f, p3 = 0.f;
        p0 = fmaf(__shfl(A, idxA[0], 32), bflo(q0.x), p0);
        p1 = fmaf(__shfl(A, idxA[1], 32), bfhi(q0.x), p1);
        p2 = fmaf(__shfl(A, idxA[2], 32), bflo(q0.y), p2);
        p3 = fmaf(__shfl(A, idxA[3], 32), bfhi(q0.y), p3);
        p0 = fmaf(__shfl(A, idxA[4], 32), bflo(q0.z), p0);
        p1 = fmaf(__shfl(A, idxA[5], 32), bfhi(q0.z), p1);
        p2 = fmaf(__shfl(A, idxA[6], 32), bflo(q0.w), p2);
        p3 = fmaf(__shfl(A, idxA[7], 32), bfhi(q0.w), p3);
        p0 = fmaf(__shfl(A, idxB[0], 32), bflo(q1.x), p0);
        p1 = fmaf(__shfl(A, idxB[1], 32), bfhi(q1.x), p1);
        p2 = fmaf(__shfl(A, idxB[2], 32), bflo(q1.y), p2);
        p3 = fmaf(__shfl(A, idxB[3], 32), bfhi(q1.y), p3);
        p0 = fmaf(__shfl(A, idxB[4], 32), bflo(q1.z), p0);
        p1 = fmaf(__shfl(A, idxB[5], 32), bfhi(q1.z), p1);
        p2 = fmaf(__shfl(A, idxB[6], 32), bflo(q1.w), p2);
        p3 = fmaf(__shfl(A, idxB[7], 32), bfhi(q1.w), p3);
        float part = (p0 + p1) + (p2 + p3);
        part += __shfl_xor(part, 32);           // fold half-wave partials

        float mm = part;
        #pragma unroll
        for (int d = 16; d > 0; d >>= 1) mm = fmaxf(mm, __shfl_xor(mm, d, 32));
        A = part / mm;
        Lacc += __logf(mm);
        q0 = n0; q1 = n1;
    }

    if (h == 0) sm[w * 32 + n] = A;
    if (lane == 0) { sm[64 + w] = Lacc; sm[66 + w] = ntot; }
    __syncthreads();

    if (threadIdx.x < 32) {
        float v = sm[threadIdx.x] * sm[32 + threadIdx.x];
        #pragma unroll
        for (int d = 16; d > 0; d >>= 1) v += __shfl_xor(v, d, 32);
        if (threadIdx.x == 0) {
            const float part = sm[64] + sm[65] + __logf(v) + (sm[66] + sm[67]) * SCALE_LOG;
            const int len = (int)(wsflt[WS_MSUM_OFF + b] + 0.5f);
            const int lt  = tags[b * S_N + len - 1];
            atomicAdd(out, part - endT[lt] - wsflt[WS_SCORE_OFF + b]);
        }
    }
}

extern "C" void kernel_launch(void* const* d_in, const int* in_sizes, int n_in,
                              void* d_out, int out_size, void* d_ws, size_t ws_size,
                              hipStream_t stream) {
    const float* em     = (const float*)d_in[0];
    const int*   tags   = (const int*)  d_in[1];
    const float* mask   = (const float*)d_in[2];
    const float* trans  = (const float*)d_in[3];
    const float* startT = (const float*)d_in[4];
    const float* endT   = (const float*)d_in[5];
    float* out = (float*)d_out;

    unsigned* wsf   = (unsigned*)d_ws;
    float*    wsflt = (float*)d_ws;

    hipMemsetAsync(out, 0, sizeof(float), stream);
    hipMemsetAsync((char*)d_ws + WS_MSUM_OFF * 4, 0, 4096, stream);

    hipLaunchKernelGGL(crf_chunk, dim3(2048), dim3(256), 0, stream,
                       em, tags, mask, trans, startT, wsf, wsflt);
    hipLaunchKernelGGL(crf_combine, dim3(512), dim3(128), 0, stream,
                       em, tags, startT, endT, wsf, wsflt, out);
}

// Round 5
// 173.218 us; speedup vs baseline: 1.4702x; 1.0291x over previous
//
#include <hip/hip_runtime.h>

// CRF NLL on MI355X — round 5: 4 interleaved chains per wave (ILP vs latency).
//
// partition_b = log( a0 . (prod_t M_t) . exp(end) ),  M_t = ET . diag(ee_t).
// r4's PI-aligned MFMA step (C/D reg order == next B operand order; zero
// cross-lane ops) kept verbatim, but each wave now runs FOUR independent
// chunk chains interleaved — the ~400cyc/step MFMA->pack->MFMA dependency
// stall of one chain is filled by the other three. Block = one batch:
// 4 waves x 4 chunks = 16 chunks, 64 KiB LDS, exactly 2 blocks/CU.
// All chunks are forward products now (no transposed variant); combine is a
// single 16-step vector chain per batch. Path score fused into chunk kernel.
// Fixed 2^-7 per-matrix scaling (exact: added back as napp*7*ln2).
//
// ws: [0,16MiB) fragments (8 dw/lane per (b,c)); then msum[512], score[512],
//     napp[512*16].

typedef __attribute__((ext_vector_type(8)))  short    short8;
typedef __attribute__((ext_vector_type(16))) float    f32x16;
typedef __attribute__((ext_vector_type(4)))  unsigned uint4v;

#define S_N 1024
#define T_N 32
#define B_N 512
#define L_CH 64
#define C_CH 16
#define SCALE_MUL 0.0078125f           // 2^-7 folded into ee
#define SCALE_LOG 4.852030263919617f   // 7*ln2 per applied matrix

#define WS_FRAG_DW ((size_t)B_N * C_CH * 512)          // 16 MiB
#define WS_MSUM_OFF (WS_FRAG_DW)
#define WS_SCORE_OFF (WS_FRAG_DW + 512)
#define WS_NAPP_OFF (WS_FRAG_DW + 1024)

#if __has_builtin(__builtin_amdgcn_cvt_pk_bf16_f32)
typedef __attribute__((ext_vector_type(2))) __bf16 bf16x2;
__device__ __forceinline__ unsigned cvtpk(float lo, float hi) {
    return __builtin_bit_cast(unsigned, __builtin_amdgcn_cvt_pk_bf16_f32(lo, hi));
}
#else
__device__ __forceinline__ unsigned cvtpk(float lo, float hi) {
    const unsigned a = __float_as_uint(lo) + 0x8000u;
    const unsigned b = __float_as_uint(hi) + 0x8000u;
    return __builtin_amdgcn_perm(b, a, 0x07060302u);
}
#endif

__device__ __forceinline__ short8 mk8(const unsigned* a) {
    uint4v u = {a[0], a[1], a[2], a[3]};
    return __builtin_bit_cast(short8, u);
}
__device__ __forceinline__ float bflo(unsigned u) { return __uint_as_float(u << 16); }
__device__ __forceinline__ float bfhi(unsigned u) { return __uint_as_float(u & 0xFFFF0000u); }
// PI: involution swapping rows 4-7<->8-11 and 20-23<->24-27
__device__ __forceinline__ int PIx(int x) { return (x & ~12) | ((x & 4) << 1) | ((x & 8) >> 1); }

__global__ __launch_bounds__(256, 2) void crf_chunk(
    const float* __restrict__ em, const int* __restrict__ tags,
    const float* __restrict__ mask, const float* __restrict__ trans,
    const float* __restrict__ startT, unsigned* __restrict__ wsf,
    float* __restrict__ wsflt)
{
    __shared__ unsigned elds[16384];   // 64 KiB: 4 waves x 4 chunks x 1024 dw
    const int wib  = threadIdx.x >> 6;
    const int lane = threadIdx.x & 63;
    const int n    = lane & 31;
    const int h    = lane >> 5;
    const int b    = blockIdx.x;

    // ---- stage packed scales for this wave's 4 chunks ----
    // dword (r, m=h*8+q') = bf16x2(ee[r][base(m)], ee[r][base(m)+1]) in D-reg-pair order
    #pragma unroll
    for (int q = 0; q < 4; ++q) {
        const float* eq = em + ((size_t)b * S_N + (4 * wib + q) * L_CH) * T_N;
        unsigned* mq = elds + wib * 4096 + q * 1024;
        #pragma unroll
        for (int i = 0; i < 16; ++i) {
            const int flat = i * 64 + lane;
            const int r = flat >> 4, m = flat & 15;
            const int base = ((m & 4) << 2) + ((m & 2) << 2) + ((m & 1) << 1) + ((m >> 3) << 2);
            const float2 v = *(const float2*)(eq + r * 32 + base);
            mq[r * 16 + m] = cvtpk(__expf(v.x) * SCALE_MUL, __expf(v.y) * SCALE_MUL);
        }
    }

    // ---- mask ballots + fused path-score partial (4 chunks per wave) ----
    unsigned long long mb_[4];
    {
        float vacc = 0.f, macc = 0.f;
        #pragma unroll
        for (int q = 0; q < 4; ++q) {
            const int c = 4 * wib + q;
            const int s = c * L_CH + lane;
            const float mv = mask[b * S_N + s];
            unsigned long long mb = __ballot(mv != 0.0f);
            if (c == 0) mb &= ~1ull;
            mb_[q] = mb;
            const int tc = tags[b * S_N + s];
            int tp = __shfl_up(tc, 1, 64);
            float val;
            if (lane == 0) {
                if (c == 0) {
                    val = startT[tc] + em[(size_t)b * S_N * T_N + tc];
                } else {
                    tp = tags[b * S_N + s - 1];
                    val = mv * (em[((size_t)b * S_N + s) * T_N + tc] + trans[tp * 32 + tc]);
                }
            } else {
                val = mv * (em[((size_t)b * S_N + s) * T_N + tc] + trans[tp * 32 + tc]);
            }
            vacc += val; macc += mv;
            if (lane == 0) wsflt[WS_NAPP_OFF + b * C_CH + c] = (float)__popcll(mb);
        }
        #pragma unroll
        for (int d = 32; d > 0; d >>= 1) {
            vacc += __shfl_xor(vacc, d, 64);
            macc += __shfl_xor(macc, d, 64);
        }
        if (lane == 0) {
            atomicAdd(&wsflt[WS_SCORE_OFF + b], vacc);
            atomicAdd(&wsflt[WS_MSUM_OFF + b], macc);
        }
    }

    // ---- loop-invariant A fragments (PI-permuted columns of exp(trans)) ----
    unsigned A1[4], A2[4];
    #pragma unroll
    for (int j = 0; j < 4; ++j) {
        const int k1 = PIx(8 * h + 2 * j);
        const int k2 = PIx(16 + 8 * h + 2 * j);
        A1[j] = cvtpk(__expf(trans[n * 32 + k1]), __expf(trans[n * 32 + k1 + 1]));
        A2[j] = cvtpk(__expf(trans[n * 32 + k2]), __expf(trans[n * 32 + k2 + 1]));
    }
    const short8 A1v = mk8(A1), A2v = mk8(A2);
    const f32x16 Zacc = {};

    // ---- 4 chain states: identity in C layout ----
    f32x16 D0, D1, D2, D3;
    #pragma unroll
    for (int i = 0; i < 16; ++i) {
        const int row = (i & 3) + 8 * (i >> 2) + 4 * h;
        const float v = (row == n) ? 1.0f : 0.0f;
        D0[i] = v; D1[i] = v; D2[i] = v; D3[i] = v;
    }

    const unsigned* m0 = elds + wib * 4096;
    const unsigned* m1 = m0 + 1024;
    const unsigned* m2 = m0 + 2048;
    const unsigned* m3 = m0 + 3072;

    #define STEP(D, mq, r_) { \
        const uint4 su = *(const uint4*)((mq) + (r_) * 16 + h * 8); \
        const uint4 sv = *(const uint4*)((mq) + (r_) * 16 + h * 8 + 4); \
        unsigned S[8]; \
        S[0] = cvtpk(D[0]  * bflo(su.x), D[1]  * bfhi(su.x)); \
        S[1] = cvtpk(D[2]  * bflo(su.y), D[3]  * bfhi(su.y)); \
        S[2] = cvtpk(D[4]  * bflo(su.z), D[5]  * bfhi(su.z)); \
        S[3] = cvtpk(D[6]  * bflo(su.w), D[7]  * bfhi(su.w)); \
        S[4] = cvtpk(D[8]  * bflo(sv.x), D[9]  * bfhi(sv.x)); \
        S[5] = cvtpk(D[10] * bflo(sv.y), D[11] * bfhi(sv.y)); \
        S[6] = cvtpk(D[12] * bflo(sv.z), D[13] * bfhi(sv.z)); \
        S[7] = cvtpk(D[14] * bflo(sv.w), D[15] * bfhi(sv.w)); \
        f32x16 t_ = __builtin_amdgcn_mfma_f32_32x32x16_bf16(A1v, mk8(&S[0]), Zacc, 0, 0, 0); \
        D = __builtin_amdgcn_mfma_f32_32x32x16_bf16(A2v, mk8(&S[4]), t_, 0, 0, 0); \
    }

    const bool allclean =
        ((mb_[0] | ((4 * wib) == 0 ? 1ull : 0ull)) == ~0ull) &&
        (mb_[1] == ~0ull) && (mb_[2] == ~0ull) && (mb_[3] == ~0ull);

    if (allclean) {
        #pragma unroll 2
        for (int r = L_CH - 1; r >= 1; --r) {
            STEP(D0, m0, r); STEP(D1, m1, r); STEP(D2, m2, r); STEP(D3, m3, r);
        }
        if (mb_[0] & 1ull) STEP(D0, m0, 0);   // c==0 has bit0 cleared
        if (mb_[1] & 1ull) STEP(D1, m1, 0);
        if (mb_[2] & 1ull) STEP(D2, m2, 0);
        if (mb_[3] & 1ull) STEP(D3, m3, 0);
    } else {
        for (int r = L_CH - 1; r >= 0; --r) {
            if ((mb_[0] >> r) & 1ull) STEP(D0, m0, r);
            if ((mb_[1] >> r) & 1ull) STEP(D1, m1, r);
            if ((mb_[2] >> r) & 1ull) STEP(D2, m2, r);
            if ((mb_[3] >> r) & 1ull) STEP(D3, m3, r);
        }
    }
    #undef STEP

    #define STORE(D, q_) { \
        unsigned* dst = wsf + ((size_t)(b * C_CH + 4 * wib + (q_)) * 64 + lane) * 8; \
        ((uint4*)dst)[0] = make_uint4(cvtpk(D[0], D[1]),   cvtpk(D[2], D[3]), \
                                      cvtpk(D[4], D[5]),   cvtpk(D[6], D[7])); \
        ((uint4*)dst)[1] = make_uint4(cvtpk(D[8], D[9]),   cvtpk(D[10], D[11]), \
                                      cvtpk(D[12], D[13]), cvtpk(D[14], D[15])); \
    }
    STORE(D0, 0) STORE(D1, 1) STORE(D2, 2) STORE(D3, 3)
    #undef STORE
}

// one wave per batch: 16-step alpha row-vector chain over the chunk products
__global__ __launch_bounds__(256) void crf_combine(
    const float* __restrict__ em, const int* __restrict__ tags,
    const float* __restrict__ startT, const float* __restrict__ endT,
    const unsigned* __restrict__ wsf, const float* __restrict__ wsflt,
    float* __restrict__ out)
{
    const int lane = threadIdx.x & 63;
    const int n = lane & 31, h = lane >> 5;
    const int b = blockIdx.x * 4 + (threadIdx.x >> 6);

    int idxA[8], idxB[8];
    #pragma unroll
    for (int j = 0; j < 8; ++j) {
        idxA[j] = PIx(8 * h + j);
        idxB[j] = PIx(16 + 8 * h + j);
    }

    float a0 = startT[n] + em[(size_t)b * S_N * T_N + n];
    float m = a0;
    #pragma unroll
    for (int d = 16; d > 0; d >>= 1) m = fmaxf(m, __shfl_xor(m, d, 32));
    float A = __expf(a0 - m);
    float Lacc = m;
    float ntot = (lane < 16) ? wsflt[WS_NAPP_OFF + b * C_CH + lane] : 0.0f;

    const uint4* fb = (const uint4*)(wsf + (size_t)b * C_CH * 512);
    uint4 q0 = fb[lane * 2];
    uint4 q1 = fb[lane * 2 + 1];

    for (int c = 0; c < C_CH; ++c) {
        uint4 n0 = q0, n1 = q1;
        if (c + 1 < C_CH) {                      // prefetch next chunk's fragment
            n0 = fb[(c + 1) * 128 + lane * 2];
            n1 = fb[(c + 1) * 128 + lane * 2 + 1];
        }

        float p0 = 0.f, p1 = 0.f, p2 = 0.f, p3 = 0.f;
        p0 = fmaf(__shfl(A, idxA[0], 32), bflo(q0.x), p0);
        p1 = fmaf(__shfl(A, idxA[1], 32), bfhi(q0.x), p1);
        p2 = fmaf(__shfl(A, idxA[2], 32), bflo(q0.y), p2);
        p3 = fmaf(__shfl(A, idxA[3], 32), bfhi(q0.y), p3);
        p0 = fmaf(__shfl(A, idxA[4], 32), bflo(q0.z), p0);
        p1 = fmaf(__shfl(A, idxA[5], 32), bfhi(q0.z), p1);
        p2 = fmaf(__shfl(A, idxA[6], 32), bflo(q0.w), p2);
        p3 = fmaf(__shfl(A, idxA[7], 32), bfhi(q0.w), p3);
        p0 = fmaf(__shfl(A, idxB[0], 32), bflo(q1.x), p0);
        p1 = fmaf(__shfl(A, idxB[1], 32), bfhi(q1.x), p1);
        p2 = fmaf(__shfl(A, idxB[2], 32), bflo(q1.y), p2);
        p3 = fmaf(__shfl(A, idxB[3], 32), bfhi(q1.y), p3);
        p0 = fmaf(__shfl(A, idxB[4], 32), bflo(q1.z), p0);
        p1 = fmaf(__shfl(A, idxB[5], 32), bfhi(q1.z), p1);
        p2 = fmaf(__shfl(A, idxB[6], 32), bflo(q1.w), p2);
        p3 = fmaf(__shfl(A, idxB[7], 32), bfhi(q1.w), p3);
        float part = (p0 + p1) + (p2 + p3);
        part += __shfl_xor(part, 32);           // fold half-wave partials

        float mm = part;
        #pragma unroll
        for (int d = 16; d > 0; d >>= 1) mm = fmaxf(mm, __shfl_xor(mm, d, 32));
        A = part / mm;
        Lacc += __logf(mm);
        q0 = n0; q1 = n1;
    }

    float v = A * __expf(endT[n]);
    #pragma unroll
    for (int d = 16; d > 0; d >>= 1) {
        v    += __shfl_xor(v, d, 32);
        ntot += __shfl_xor(ntot, d, 32);
    }
    if (lane == 0) {
        const int len = (int)(wsflt[WS_MSUM_OFF + b] + 0.5f);
        const int lt  = tags[b * S_N + len - 1];
        const float res = Lacc + __logf(v) + ntot * SCALE_LOG
                          - endT[lt] - wsflt[WS_SCORE_OFF + b];
        atomicAdd(out, res);
    }
}

extern "C" void kernel_launch(void* const* d_in, const int* in_sizes, int n_in,
                              void* d_out, int out_size, void* d_ws, size_t ws_size,
                              hipStream_t stream) {
    const float* em     = (const float*)d_in[0];
    const int*   tags   = (const int*)  d_in[1];
    const float* mask   = (const float*)d_in[2];
    const float* trans  = (const float*)d_in[3];
    const float* startT = (const float*)d_in[4];
    const float* endT   = (const float*)d_in[5];
    float* out = (float*)d_out;

    unsigned* wsf   = (unsigned*)d_ws;
    float*    wsflt = (float*)d_ws;

    hipMemsetAsync(out, 0, sizeof(float), stream);
    hipMemsetAsync((char*)d_ws + WS_MSUM_OFF * 4, 0, 4096, stream);

    // one block per batch: 4 waves x 4 chunks; 64 KiB LDS -> 2 blocks/CU
    hipLaunchKernelGGL(crf_chunk, dim3(512), dim3(256), 0, stream,
                       em, tags, mask, trans, startT, wsf, wsflt);
    hipLaunchKernelGGL(crf_combine, dim3(128), dim3(256), 0, stream,
                       em, tags, startT, endT, wsf, wsflt, out);
}